// Round 2
// baseline (118.258 us; speedup 1.0000x reference)
//
#include <hip/hip_runtime.h>

#define NROW 8192
#define DIM  128
#define BI   128
#define NB   (NROW / BI)            // 64 row-blocks
#define NT   (NB * (NB + 1) / 2)    // 2080 upper-triangular tiles
#define BIGF 1e30f

typedef __attribute__((ext_vector_type(8))) short bf16x8;
typedef __attribute__((ext_vector_type(4))) float f32x4;

// ws layout (bytes):
//   [0, 2 MB)            xb   : 8192x128 bf16 (ushort), linear row-major
//   [+0, +32 KB)         sq   : 8192 f32 row sq-norms (fp32-exact)
//   [+32, +64 KB)        posb : 8192 u32 (d^2 as float bits, atomicMax)
//   [+64, +96 KB)        negb : 8192 u32 (d^2 as float bits, atomicMin)

__device__ __forceinline__ unsigned short f2bf(float f) {
    unsigned u = __float_as_uint(f);
    unsigned r = (u + 0x7fffu + ((u >> 16) & 1u)) >> 16;   // RNE
    return (unsigned short)r;
}

// async global->LDS, 16B per lane; LDS dest is wave-uniform base + lane*16
__device__ __forceinline__ void gload_lds16(const void* g, void* l) {
    __builtin_amdgcn_global_load_lds(
        (const __attribute__((address_space(1))) void*)g,
        (__attribute__((address_space(3))) void*)l, 16, 0, 0);
}

__global__ __launch_bounds__(256) void prep_kernel(const float* __restrict__ x,
                                                   unsigned short* __restrict__ xb,
                                                   float* __restrict__ sq,
                                                   unsigned* __restrict__ posb,
                                                   unsigned* __restrict__ negb,
                                                   float* __restrict__ out) {
    int gtid = blockIdx.x * 256 + threadIdx.x;
    if (gtid < NROW) {
        posb[gtid] = 0u;                       // 0.0f
        negb[gtid] = __float_as_uint(BIGF);
    }
    if (gtid == 0) out[0] = 0.0f;
    // one wave per row (grid 2048*256/64 == 8192 rows exactly)
    int row  = gtid >> 6;
    int lane = threadIdx.x & 63;
    const float* xr = x + (size_t)row * DIM;
    float a = xr[lane];
    float b = xr[lane + 64];
    xb[(size_t)row * DIM + lane]      = f2bf(a);
    xb[(size_t)row * DIM + lane + 64] = f2bf(b);
    float s = a * a + b * b;
    #pragma unroll
    for (int o = 32; o > 0; o >>= 1) s += __shfl_down(s, o);
    if (lane == 0) sq[row] = s;
}

// Symmetric version: one 128x128 tile per block, upper triangle only.
// Each tile updates BOTH row extrema (rows of rb) and column extrema (rows of cb).
// max/min atomics are idempotent, so diagonal-block double-coverage is harmless.
__global__ __launch_bounds__(256, 2) void tri_mfma(const unsigned short* __restrict__ xb,
                                                   const int* __restrict__ lbl,
                                                   const float* __restrict__ sq,
                                                   unsigned* __restrict__ posb,
                                                   unsigned* __restrict__ negb) {
    __shared__ unsigned short As[BI * DIM];   // 32 KB, linear + XOR-swizzled chunks
    __shared__ unsigned short Bs_[BI * DIM];  // 32 KB -> 64 KB total, 2 blocks/CU

    // ---- triangular decode: bid -> (rb, cb), cb >= rb ----
    const int bid = blockIdx.x;
    int rb = (int)(64.5f - sqrtf(64.5f * 64.5f - 2.0f * (float)bid));
    while (rb * NB - rb * (rb - 1) / 2 > bid) rb--;
    while ((rb + 1) * NB - (rb + 1) * rb / 2 <= bid) rb++;
    const int cb = rb + (bid - (rb * NB - rb * (rb - 1) / 2));
    const int i0 = rb * BI;
    const int j0 = cb * BI;

    const int t    = threadIdx.x;
    const int lane = t & 63;
    const int w    = t >> 6;
    const int wrow = (w >> 1) * 64;  // wave 2x2 grid over the 128x128 tile
    const int wcol = (w & 1) * 64;
    const int quad = lane >> 4;
    const int l15  = lane & 15;

    // ---- stage A (and B if distinct) via global_load_lds ----
    // LDS dest linear; swizzle (c16 ^= row&7) pre-applied to the GLOBAL source
    // address (rule 21), re-applied on every ds_read. Keeps ds_read_b128 at
    // 2-way bank aliasing (free) without padding.
    #pragma unroll
    for (int i = 0; i < 8; i++) {
        int L    = i * 4096 + t * 16;           // linear byte in 32 KB tile
        int row  = L >> 8;                      // 0..127
        int c16s = ((L >> 4) & 15) ^ (row & 7); // swizzled 16B-chunk
        void* ldst = (char*)As + i * 4096 + w * 1024;   // wave-uniform base
        gload_lds16(xb + (size_t)(i0 + row) * DIM + c16s * 8, ldst);
        if (cb != rb) {
            void* ldstB = (char*)Bs_ + i * 4096 + w * 1024;
            gload_lds16(xb + (size_t)(j0 + row) * DIM + c16s * 8, ldstB);
        }
    }
    const unsigned short* Bs = (cb == rb) ? As : Bs_;

    // per-lane row metadata: rows i0 + wrow + ti*16 + quad*4 + r
    float sqi[4][4];
    int   lbli[4][4];
    #pragma unroll
    for (int ti = 0; ti < 4; ti++) {
        int rbase = i0 + wrow + ti * 16 + quad * 4;
        float4 s4 = *(const float4*)(sq + rbase);
        int4   l4 = *(const int4*)(lbl + rbase);
        sqi[ti][0] = s4.x; sqi[ti][1] = s4.y; sqi[ti][2] = s4.z; sqi[ti][3] = s4.w;
        lbli[ti][0] = l4.x; lbli[ti][1] = l4.y; lbli[ti][2] = l4.z; lbli[ti][3] = l4.w;
    }
    // column metadata: cols j0 + wcol + tj*16 + l15
    float sqj[4]; int lblj[4];
    #pragma unroll
    for (int tj = 0; tj < 4; tj++) {
        int c = j0 + wcol + tj * 16 + l15;
        sqj[tj]  = sq[c];
        lblj[tj] = lbl[c];
    }

    __syncthreads();   // drains the global_load_lds queue (vmcnt 0) for all waves

    // ---- A fragments into registers (each block consumes A exactly once) ----
    bf16x8 af[4][4];
    #pragma unroll
    for (int ti = 0; ti < 4; ti++)
        #pragma unroll
        for (int ks = 0; ks < 4; ks++) {
            int r    = wrow + ti * 16 + l15;
            int c16s = (ks * 4 + quad) ^ (l15 & 7);   // row&7 == l15&7 here
            af[ti][ks] = *(const bf16x8*)((const char*)As + r * 256 + c16s * 16);
        }

    f32x4 acc[4][4];
    #pragma unroll
    for (int ti = 0; ti < 4; ti++)
        #pragma unroll
        for (int tj = 0; tj < 4; tj++) acc[ti][tj] = (f32x4){0.f, 0.f, 0.f, 0.f};

    #pragma unroll
    for (int ks = 0; ks < 4; ks++) {
        bf16x8 bfr[4];
        #pragma unroll
        for (int tj = 0; tj < 4; tj++) {
            int r    = wcol + tj * 16 + l15;
            int c16s = (ks * 4 + quad) ^ (l15 & 7);
            bfr[tj] = *(const bf16x8*)((const char*)Bs + r * 256 + c16s * 16);
        }
        #pragma unroll
        for (int ti = 0; ti < 4; ti++)
            #pragma unroll
            for (int tj = 0; tj < 4; tj++)
                acc[ti][tj] = __builtin_amdgcn_mfma_f32_16x16x32_bf16(af[ti][ks], bfr[tj], acc[ti][tj], 0, 0, 0);
    }

    // ---- dual epilogue: row extrema (s = sqj - 2dot) and col extrema (s = sqi - 2dot)
    const bool diag = (rb == cb) && (wrow == wcol);   // wave tile touches the diagonal
    float posm[4][4], negm[4][4];
    float colp[4], coln[4];
    #pragma unroll
    for (int ti = 0; ti < 4; ti++)
        #pragma unroll
        for (int r = 0; r < 4; r++) { posm[ti][r] = -BIGF; negm[ti][r] = BIGF; }
    #pragma unroll
    for (int tj = 0; tj < 4; tj++) { colp[tj] = -BIGF; coln[tj] = BIGF; }

    #pragma unroll
    for (int ti = 0; ti < 4; ti++)
        #pragma unroll
        for (int tj = 0; tj < 4; tj++)
            #pragma unroll
            for (int r = 0; r < 4; r++) {
                float d  = acc[ti][tj][r];
                float sr = fmaf(-2.0f, d, sqj[tj]);      // d^2 - sqi  (row view)
                float sc = fmaf(-2.0f, d, sqi[ti][r]);   // d^2 - sqj  (col view)
                bool same = (lbli[ti][r] == lblj[tj]);
                bool isd  = diag && (ti == tj) && (quad * 4 + r == l15);
                bool okp  = same && !isd;
                posm[ti][r] = fmaxf(posm[ti][r], okp  ? sr : -BIGF);
                negm[ti][r] = fminf(negm[ti][r], same ? BIGF : sr);
                colp[tj]    = fmaxf(colp[tj],    okp  ? sc : -BIGF);
                coln[tj]    = fminf(coln[tj],    same ? BIGF : sc);
            }

    // row reduce across the 16 column-lanes; one atomic per row
    #pragma unroll
    for (int ti = 0; ti < 4; ti++)
        #pragma unroll
        for (int r = 0; r < 4; r++) {
            float p = posm[ti][r];
            float n = negm[ti][r];
            #pragma unroll
            for (int m = 8; m >= 1; m >>= 1) {
                p = fmaxf(p, __shfl_xor(p, m));
                n = fminf(n, __shfl_xor(n, m));
            }
            if (l15 == 0) {
                int row = i0 + wrow + ti * 16 + quad * 4 + r;
                float d2p = fmaxf(0.0f, sqi[ti][r] + p);   // no positive -> 0
                float d2n = fmaxf(0.0f, sqi[ti][r] + n);   // clamp bf16-noise negatives
                atomicMax(&posb[row], __float_as_uint(d2p));
                atomicMin(&negb[row], __float_as_uint(d2n));
            }
        }

    // col reduce across the 4 quad-lane-groups; one atomic per column
    #pragma unroll
    for (int tj = 0; tj < 4; tj++) {
        float p = colp[tj];
        float n = coln[tj];
        p = fmaxf(p, __shfl_xor(p, 16));
        p = fmaxf(p, __shfl_xor(p, 32));
        n = fminf(n, __shfl_xor(n, 16));
        n = fminf(n, __shfl_xor(n, 32));
        if (quad == 0) {
            int col = j0 + wcol + tj * 16 + l15;
            float d2p = fmaxf(0.0f, sqj[tj] + p);
            float d2n = fmaxf(0.0f, sqj[tj] + n);
            atomicMax(&posb[col], __float_as_uint(d2p));
            atomicMin(&negb[col], __float_as_uint(d2n));
        }
    }
}

__global__ __launch_bounds__(256) void tri_final(const unsigned* __restrict__ posb,
                                                 const unsigned* __restrict__ negb,
                                                 const float* __restrict__ margin,
                                                 float* __restrict__ out) {
    int r = blockIdx.x * 256 + threadIdx.x;
    float m = margin[0];
    float p  = sqrtf(__uint_as_float(posb[r]));
    float ng = sqrtf(__uint_as_float(negb[r]));
    float loss = fmaxf(p - ng + m, 0.0f) * (1.0f / (float)NROW);
    #pragma unroll
    for (int o = 32; o > 0; o >>= 1) loss += __shfl_down(loss, o);
    __shared__ float wsum[4];
    int lane = threadIdx.x & 63, wv = threadIdx.x >> 6;
    if (lane == 0) wsum[wv] = loss;
    __syncthreads();
    if (threadIdx.x == 0) atomicAdd(out, wsum[0] + wsum[1] + wsum[2] + wsum[3]);
}

extern "C" void kernel_launch(void* const* d_in, const int* in_sizes, int n_in,
                              void* d_out, int out_size, void* d_ws, size_t ws_size,
                              hipStream_t stream) {
    const float* x      = (const float*)d_in[0];
    const int*   lbl    = (const int*)d_in[1];
    const float* margin = (const float*)d_in[2];
    float* out = (float*)d_out;

    unsigned short* xb = (unsigned short*)d_ws;                       // 2 MB
    float*    sq   = (float*)((char*)d_ws + (size_t)NROW * DIM * 2);
    unsigned* posb = (unsigned*)((char*)sq + NROW * 4);
    unsigned* negb = posb + NROW;

    prep_kernel<<<2048, 256, 0, stream>>>(x, xb, sq, posb, negb, out);
    tri_mfma<<<NT, 256, 0, stream>>>(xb, lbl, sq, posb, negb);
    tri_final<<<NROW / 256, 256, 0, stream>>>(posb, negb, margin, out);
}

// Round 4
// 97.579 us; speedup vs baseline: 1.2119x; 1.2119x over previous
//
#include <hip/hip_runtime.h>

#define NROW 8192
#define DIM  128
#define NLBL 512
#define JSPLIT 8
#define NSEG  (JSPLIT * 2)          // column partials: 8 chunks x 2 wave-halves
#define BIGF 1e30f

typedef __attribute__((ext_vector_type(8))) short bf16x8;
typedef __attribute__((ext_vector_type(4))) float f32x4;

// ws layout (bytes):
//   [0, 2 MB)              xb2     : bf16 data, FRAGMENT-MAJOR: group g=row>>4 (512),
//                                    chunk c=0..15 (16B each), slot row&15 -> every MFMA
//                                    fragment load is a contiguous 1KB per wave instr
//   2MB + [0,  32 KB)      sq      : f32 row sq-norms (sorted order, fp32-exact)
//   2MB + [32, 64 KB)      rowBand : u32 = binLo | binHi<<16 (sorted-space label band)
//   2MB + [64, 68 KB)      binStart: 513 i32
//   2MB + [68, 72 KB)      cursor  : 512 u32
//   2MB + [128, 640 KB)    posS    : [NSEG][NROW] f32 partial hardest-pos d^2
//   2MB + [640, 1152 KB)   negS    : [NSEG][NROW] f32 partial hardest-neg d^2

__device__ __forceinline__ unsigned short f2bf(float f) {
    unsigned u = __float_as_uint(f);
    unsigned r = (u + 0x7fffu + ((u >> 16) & 1u)) >> 16;   // RNE
    return (unsigned short)r;
}

// 1 block: histogram labels, prefix-scan to bin starts, init cursors + out.
__global__ __launch_bounds__(1024) void prep_sort(const int* __restrict__ lbl,
                                                  int* __restrict__ binStart,
                                                  unsigned* __restrict__ cursor,
                                                  float* __restrict__ out) {
    __shared__ int hist[NLBL];
    __shared__ int scan[NLBL];
    const int t = threadIdx.x;
    if (t < NLBL) hist[t] = 0;
    __syncthreads();
    #pragma unroll
    for (int k = 0; k < NROW / 1024; k++)
        atomicAdd(&hist[lbl[t + k * 1024]], 1);
    __syncthreads();
    if (t < NLBL) scan[t] = hist[t];
    __syncthreads();
    for (int off = 1; off < NLBL; off <<= 1) {
        int v = 0;
        if (t < NLBL && t >= off) v = scan[t - off];
        __syncthreads();
        if (t < NLBL) scan[t] += v;
        __syncthreads();
    }
    if (t < NLBL) {
        int st = scan[t] - hist[t];          // exclusive prefix
        binStart[t] = st;
        cursor[t]   = (unsigned)st;
    }
    if (t == 0) { binStart[NLBL] = NROW; out[0] = 0.0f; }
}

// 16 lanes per row: bf16-convert + scatter to sorted slot in fragment-major layout,
// fp32 sq-norm, and the row's label band [binStart[l], binStart[l+1]).
__global__ __launch_bounds__(256) void prep_scatter(const float* __restrict__ x,
                                                    const int* __restrict__ lbl,
                                                    const int* __restrict__ binStart,
                                                    unsigned* __restrict__ cursor,
                                                    unsigned short* __restrict__ xb2,
                                                    float* __restrict__ sq,
                                                    unsigned* __restrict__ rowBand) {
    const int t   = threadIdx.x;
    const int row = blockIdx.x * 16 + (t >> 4);
    const int c   = t & 15;                     // 16B chunk of the row
    const float* xr = x + (size_t)row * DIM + c * 8;
    float4 f0 = *(const float4*)xr;
    float4 f1 = *(const float4*)(xr + 4);
    float s = f0.x*f0.x + f0.y*f0.y + f0.z*f0.z + f0.w*f0.w
            + f1.x*f1.x + f1.y*f1.y + f1.z*f1.z + f1.w*f1.w;
    #pragma unroll
    for (int m = 1; m <= 8; m <<= 1) s += __shfl_xor(s, m);   // stays in 16-group
    const int l = lbl[row];
    unsigned p = 0;
    if (c == 0) p = atomicAdd(&cursor[l], 1u);  // sorted destination slot
    p = __shfl((int)p, t & 48);                 // broadcast within the 16-group
    unsigned w0 = (unsigned)f2bf(f0.x) | ((unsigned)f2bf(f0.y) << 16);
    unsigned w1 = (unsigned)f2bf(f0.z) | ((unsigned)f2bf(f0.w) << 16);
    unsigned w2 = (unsigned)f2bf(f1.x) | ((unsigned)f2bf(f1.y) << 16);
    unsigned w3 = (unsigned)f2bf(f1.z) | ((unsigned)f2bf(f1.w) << 16);
    uint4 v = make_uint4(w0, w1, w2, w3);
    *(uint4*)(xb2 + (size_t)(p >> 4) * 2048 + c * 128 + (p & 15) * 8) = v;
    if (c == 0) {
        sq[p] = s;
        rowBand[p] = (unsigned)binStart[l] | ((unsigned)binStart[l + 1] << 16);
    }
}

// Full 8192x8192 Gram, 64 row-panels x 8 col-chunks. NO LDS, NO barriers, NO atomics:
// all fragments loaded straight from the fragment-major global layout (L2-resident),
// A-panel fragments register-resident across the 8-tile loop, extrema in registers,
// one plain store per (row, seg) at the end. seg = jq*2 + wave-col-half so the two
// waves sharing a row range never store to the same slot (v3 race fix).
__global__ __launch_bounds__(256, 2) void tile_mfma(const unsigned short* __restrict__ xb2,
                                                    const float* __restrict__ sq,
                                                    const unsigned* __restrict__ rowBand,
                                                    float* __restrict__ posS,
                                                    float* __restrict__ negS) {
    const int bid = blockIdx.x;
    const int rb  = bid >> 3;
    const int jq  = bid & 7;
    const int i0  = rb * 128;
    const int t    = threadIdx.x;
    const int lane = t & 63;
    const int w    = t >> 6;
    const int wrow = (w >> 1) * 64;   // wave 2x2 grid over the 128x128 tile
    const int wcol = (w & 1) * 64;
    const int quad = lane >> 4;
    const int l15  = lane & 15;

    // ---- A fragments: 16 contiguous-1KB loads, once per block ----
    bf16x8 af[4][4];
    const int gA = (i0 + wrow) >> 4;
    #pragma unroll
    for (int ti = 0; ti < 4; ti++)
        #pragma unroll
        for (int ks = 0; ks < 4; ks++)
            af[ti][ks] = *(const bf16x8*)(xb2 + (size_t)(gA + ti) * 2048 + (ks * 4 + quad) * 128 + l15 * 8);

    // ---- per-lane row band (4 rows per ti, this quad) ----
    unsigned band[4][4];
    #pragma unroll
    for (int ti = 0; ti < 4; ti++) {
        uint4 b4 = *(const uint4*)(rowBand + i0 + wrow + ti * 16 + quad * 4);
        band[ti][0] = b4.x; band[ti][1] = b4.y; band[ti][2] = b4.z; band[ti][3] = b4.w;
    }
    // wave-uniform band envelope per ti (sorted rows => tight)
    int tiLo[4], tiHi[4];
    #pragma unroll
    for (int ti = 0; ti < 4; ti++) {
        int lo = (int)(band[ti][0] & 0xffffu), hi = (int)(band[ti][0] >> 16);
        #pragma unroll
        for (int r = 1; r < 4; r++) {
            int l2 = (int)(band[ti][r] & 0xffffu), h2 = (int)(band[ti][r] >> 16);
            lo = lo < l2 ? lo : l2;
            hi = hi > h2 ? hi : h2;
        }
        int v;
        v = __shfl_xor(lo, 16); lo = lo < v ? lo : v;
        v = __shfl_xor(lo, 32); lo = lo < v ? lo : v;
        v = __shfl_xor(hi, 16); hi = hi > v ? hi : v;
        v = __shfl_xor(hi, 32); hi = hi > v ? hi : v;
        tiLo[ti] = __builtin_amdgcn_readfirstlane(lo);
        tiHi[ti] = __builtin_amdgcn_readfirstlane(hi);
    }

    float posm[4][4], negm[4][4];
    #pragma unroll
    for (int ti = 0; ti < 4; ti++)
        #pragma unroll
        for (int r = 0; r < 4; r++) { posm[ti][r] = -BIGF; negm[ti][r] = BIGF; }

    const int jbase = jq * 1024;
    #pragma unroll 1
    for (int jt = 0; jt < 8; jt++) {
        const int j0 = jbase + jt * 128;
        float sqj[4];
        #pragma unroll
        for (int tj = 0; tj < 4; tj++) sqj[tj] = sq[j0 + wcol + tj * 16 + l15];

        f32x4 acc[4][4];
        #pragma unroll
        for (int ti = 0; ti < 4; ti++)
            #pragma unroll
            for (int tj = 0; tj < 4; tj++) acc[ti][tj] = (f32x4){0.f, 0.f, 0.f, 0.f};

        const int gB = (j0 + wcol) >> 4;
        #pragma unroll
        for (int ks = 0; ks < 4; ks++) {
            bf16x8 bfr[4];
            #pragma unroll
            for (int tj = 0; tj < 4; tj++)
                bfr[tj] = *(const bf16x8*)(xb2 + (size_t)(gB + tj) * 2048 + (ks * 4 + quad) * 128 + l15 * 8);
            #pragma unroll
            for (int ti = 0; ti < 4; ti++)
                #pragma unroll
                for (int tj = 0; tj < 4; tj++)
                    acc[ti][tj] = __builtin_amdgcn_mfma_f32_16x16x32_bf16(af[ti][ks], bfr[tj], acc[ti][tj], 0, 0, 0);
        }

        // ---- epilogue: band-aware, wave-uniform fast/slow split ----
        #pragma unroll
        for (int ti = 0; ti < 4; ti++) {
            #pragma unroll
            for (int tj = 0; tj < 4; tj++) {
                const int colLo = j0 + wcol + tj * 16;
                if (colLo + 16 <= tiLo[ti] || colLo >= tiHi[ti]) {
                    // no same-label pair possible: pure negatives, 2 ops/elem
                    #pragma unroll
                    for (int r = 0; r < 4; r++) {
                        float sr = fmaf(-2.0f, acc[ti][tj][r], sqj[tj]);
                        negm[ti][r] = fminf(negm[ti][r], sr);
                    }
                } else {
                    const int jcol  = colLo + l15;
                    const int rowg0 = i0 + wrow + ti * 16 + quad * 4;
                    #pragma unroll
                    for (int r = 0; r < 4; r++) {
                        float sr = fmaf(-2.0f, acc[ti][tj][r], sqj[tj]);
                        const int lo = (int)(band[ti][r] & 0xffffu);
                        const int hi = (int)(band[ti][r] >> 16);
                        bool inb  = (jcol >= lo) && (jcol < hi);   // same label (incl self)
                        bool self = (jcol == rowg0 + r);
                        posm[ti][r] = fmaxf(posm[ti][r], (inb && !self) ? sr : -BIGF);
                        negm[ti][r] = fminf(negm[ti][r], inb ? BIGF : sr);
                    }
                }
            }
        }
    }

    // ---- flush: reduce across 16 col-lanes, plain store (no atomics) ----
    const int seg = jq * 2 + (wcol >> 6);   // distinct slot per wave-column half
    #pragma unroll
    for (int ti = 0; ti < 4; ti++)
        #pragma unroll
        for (int r = 0; r < 4; r++) {
            float p = posm[ti][r];
            float n = negm[ti][r];
            #pragma unroll
            for (int m = 8; m >= 1; m >>= 1) {
                p = fmaxf(p, __shfl_xor(p, m));
                n = fminf(n, __shfl_xor(n, m));
            }
            if (l15 == 0) {
                int row = i0 + wrow + ti * 16 + quad * 4 + r;
                float sqi = sq[row];
                posS[seg * NROW + row] = fmaxf(0.0f, sqi + p);   // -BIG => 0 (no positive here)
                negS[seg * NROW + row] = fmaxf(0.0f, sqi + n);   // clamp bf16-noise negatives
            }
        }
}

__global__ __launch_bounds__(256) void tri_final(const float* __restrict__ posS,
                                                 const float* __restrict__ negS,
                                                 const float* __restrict__ margin,
                                                 float* __restrict__ out) {
    int r = blockIdx.x * 256 + threadIdx.x;
    float p = 0.0f, n = BIGF;
    #pragma unroll
    for (int q = 0; q < NSEG; q++) {
        p = fmaxf(p, posS[q * NROW + r]);
        n = fminf(n, negS[q * NROW + r]);
    }
    float m = margin[0];
    float loss = fmaxf(sqrtf(p) - sqrtf(n) + m, 0.0f) * (1.0f / (float)NROW);
    #pragma unroll
    for (int o = 32; o > 0; o >>= 1) loss += __shfl_down(loss, o);
    __shared__ float wsum[4];
    int lane = threadIdx.x & 63, wv = threadIdx.x >> 6;
    if (lane == 0) wsum[wv] = loss;
    __syncthreads();
    if (threadIdx.x == 0) atomicAdd(out, wsum[0] + wsum[1] + wsum[2] + wsum[3]);
}

extern "C" void kernel_launch(void* const* d_in, const int* in_sizes, int n_in,
                              void* d_out, int out_size, void* d_ws, size_t ws_size,
                              hipStream_t stream) {
    const float* x      = (const float*)d_in[0];
    const int*   lbl    = (const int*)d_in[1];
    const float* margin = (const float*)d_in[2];
    float* out = (float*)d_out;

    char* ws = (char*)d_ws;
    unsigned short* xb2 = (unsigned short*)ws;
    float*    sq       = (float*)(ws + (2u << 20));
    unsigned* rowBand  = (unsigned*)(ws + (2u << 20) + (32u << 10));
    int*      binStart = (int*)(ws + (2u << 20) + (64u << 10));
    unsigned* cursor   = (unsigned*)(ws + (2u << 20) + (68u << 10));
    float*    posS     = (float*)(ws + (2u << 20) + (128u << 10));
    float*    negS     = (float*)(ws + (2u << 20) + (640u << 10));

    prep_sort<<<1, 1024, 0, stream>>>(lbl, binStart, cursor, out);
    prep_scatter<<<NROW / 16, 256, 0, stream>>>(x, lbl, binStart, cursor, xb2, sq, rowBand);
    tile_mfma<<<64 * JSPLIT, 256, 0, stream>>>(xb2, sq, rowBand, posS, negS);
    tri_final<<<NROW / 256, 256, 0, stream>>>(posS, negS, margin, out);
}